// Round 7
// baseline (2804.212 us; speedup 1.0000x reference)
//
#include <hip/hip_runtime.h>
#include <cstdint>

typedef __bf16 bf16_t;
typedef __bf16 bf16x8 __attribute__((ext_vector_type(8)));
typedef float  f32x4  __attribute__((ext_vector_type(4)));
typedef unsigned int u32;

#define DEPTH 6
#define HEADS 12
#define DH    64
#define DIM   768
#define MLPD  3072
#define FEAT  1000
#define BATCH 32
#define SEQ   197
#define NP    224          // padded j stride for attention matrices
#define TOK   (BATCH*SEQ)  // 6304

__device__ __forceinline__ f32x4 zero4() {
    f32x4 z; z[0] = 0.f; z[1] = 0.f; z[2] = 0.f; z[3] = 0.f; return z;
}

__device__ __forceinline__ f32x4 mfma16(bf16x8 a, bf16x8 b, f32x4 c) {
    return __builtin_amdgcn_mfma_f32_16x16x32_bf16(a, b, c, 0, 0, 0);
}

// async global->LDS, 16B per lane. lds base must be wave-uniform; HW adds lane*16.
typedef const __attribute__((address_space(1))) u32* gas_ptr;
typedef __attribute__((address_space(3))) u32*       las_ptr;
__device__ __forceinline__ void gload16(const bf16_t* g, bf16_t* l) {
    __builtin_amdgcn_global_load_lds((gas_ptr)g, (las_ptr)l, 16, 0, 0);
}

__device__ __forceinline__ void bar() {
    __builtin_amdgcn_s_barrier();
    asm volatile("" ::: "memory");
}

// ---------------- concat cls + x -> xbuf ----------------
__global__ __launch_bounds__(256) void concat_k(const float* __restrict__ x,
                                                const float* __restrict__ cls,
                                                float* __restrict__ xbuf) {
    int idx = blockIdx.x * 256 + threadIdx.x;      // exactly 6304*768 threads
    int col = idx % DIM;
    int row = idx / DIM;
    int b = row / SEQ, p = row % SEQ;
    xbuf[idx] = (p == 0) ? cls[col] : x[(b * 196 + p - 1) * DIM + col];
}

// ---------------- transpose + fp32->bf16:  W[K][N] -> Wt[N][K] ----------------
__global__ __launch_bounds__(256) void tcvt_k(const float* __restrict__ W,
                                              bf16_t* __restrict__ Wt,
                                              int K, int N) {
    __shared__ float t[32][33];
    int n0 = blockIdx.x * 32, k0 = blockIdx.y * 32;
    int c = threadIdx.x & 31, r = threadIdx.x >> 5;
#pragma unroll
    for (int i = 0; i < 4; i++) {
        int k = k0 + r + i * 8, n = n0 + c;        // K is always a multiple of 32
        t[r + i * 8][c] = (n < N) ? W[k * N + n] : 0.f;
    }
    __syncthreads();
#pragma unroll
    for (int i = 0; i < 4; i++) {
        int n = n0 + r + i * 8, k = k0 + c;
        if (n < N) Wt[n * K + k] = (bf16_t)t[c][r + i * 8];
    }
}

// ---------------- row LayerNorm over 768 cols, fp32 in -> bf16 out ----------------
__global__ __launch_bounds__(256) void ln_k(const float* __restrict__ x, long row_stride,
                                            const float* __restrict__ g,
                                            const float* __restrict__ b,
                                            bf16_t* __restrict__ out) {
    int row = blockIdx.x;
    const float* xr = x + (long)row * row_stride;
    int t = threadIdx.x;
    float v0 = xr[t], v1 = xr[t + 256], v2 = xr[t + 512];
    float s  = v0 + v1 + v2;
    float sq = v0 * v0 + v1 * v1 + v2 * v2;
#pragma unroll
    for (int o = 1; o < 64; o <<= 1) { s += __shfl_xor(s, o); sq += __shfl_xor(sq, o); }
    __shared__ float ss[4], sqs[4];
    int w = t >> 6;
    if ((t & 63) == 0) { ss[w] = s; sqs[w] = sq; }
    __syncthreads();
    s  = ss[0] + ss[1] + ss[2] + ss[3];
    sq = sqs[0] + sqs[1] + sqs[2] + sqs[3];
    float m  = s * (1.f / 768.f);
    float rs = rsqrtf(sq * (1.f / 768.f) - m * m + 1e-5f);
    bf16_t* orow = out + (long)row * DIM;
    orow[t]       = (bf16_t)((v0 - m) * rs * g[t]       + b[t]);
    orow[t + 256] = (bf16_t)((v1 - m) * rs * g[t + 256] + b[t + 256]);
    orow[t + 512] = (bf16_t)((v2 - m) * rs * g[t + 512] + b[t + 512]);
}

// ======== gemm8: 256x256 tile, BK=64, 8 waves (2Mx4N, wave 128x64), 4-phase/K-tile ======
// m201-style schedule. LDS: 2 bufs x (A 256x64 + B 256x64) = 128KB. 16B-granule XOR
// swizzle: physical slot s at row r holds logical granule s^(r&7) (both-sides, verified).
// Phases per K-tile t (buf=t&1):
//   p0: ds_read A(mh0) 8 + B(nh0) 4 -> bar -> lgkmcnt0 -> 16 MFMA q00 -> bar
//   p1: ds_read B(nh1) 4            -> bar -> lgkmcnt0 -> 16 MFMA q01 -> bar
//   p2: ds_read A(mh1) 8; stage B(t+2) [B LDS fully consumed at p1] -> ... q11 -> bar
//   p3: stage A(t+2) [A consumed at p2]; 16 MFMA q10 (regs only); vmcnt(st?8:0); bar
// vmcnt ledger: each iter issues 8 loads (B 4, A 4); at iter end, in-flight = tile t+1's 8
// + tile t+2's 8 (if staged); vmcnt(8) retires tile t+1. Prologue stages B0,A0,B1,A1 then
// vmcnt(8) retires tile 0. NT = K/64 >= 2. N multiple of 256; M clamped/guarded.
// MODE 0: Cb = acc; 1: Cf += acc + bias; 2: Cb = gelu(acc + bias)
#define MFMAQ(mh, nh)                                                        \
    _Pragma("unroll")                                                        \
    for (int mf = 0; mf < 4; mf++) {                                         \
        _Pragma("unroll")                                                    \
        for (int nf = 0; nf < 2; nf++) {                                     \
            f32x4 c = acc[(mh) * 2 + (nh)][mf * 2 + nf];                     \
            c = mfma16(aR[mf][0], bR[nh][nf][0], c);                         \
            c = mfma16(aR[mf][1], bR[nh][nf][1], c);                         \
            acc[(mh) * 2 + (nh)][mf * 2 + nf] = c;                           \
        }                                                                    \
    }

template <int MODE>
__global__ __launch_bounds__(512, 1) void gemm8_k(const bf16_t* __restrict__ A,
                                                  const bf16_t* __restrict__ Bt,
                                                  const float* __restrict__ bias,
                                                  float* __restrict__ Cf,
                                                  bf16_t* __restrict__ Cb,
                                                  int M, int N, int K, int gn) {
    __shared__ bf16_t sA[2][256 * 64];   // 64 KB
    __shared__ bf16_t sB[2][256 * 64];   // 64 KB
    int tid = threadIdx.x;
    int bm = (blockIdx.x / gn) * 256, bn = (blockIdx.x % gn) * 256;
    int wave = tid >> 6, lane = tid & 63;
    int wm = (wave >> 2) * 128, wn = (wave & 3) * 64;
    int la = lane & 15, lb = lane >> 4;

    // staging: per operand K-tile = 4 issues of 8KB (64 rows x 128B). thread: row srow,
    // slot tid&7; source col pre-swizzled so slot s holds logical granule s^(row&7).
    int srow = tid >> 3;                           // 0..63
    int scol = ((tid & 7) ^ (srow & 7)) * 8;       // elems
    int rA[4], rB[4];
#pragma unroll
    for (int i = 0; i < 4; i++) {
        int r = bm + i * 64 + srow; rA[i] = (r < M) ? r : M - 1;
        rB[i] = bn + i * 64 + srow;                // N multiple of 256
    }
    int woff = wave * 512;                         // elems within an 8KB issue

    f32x4 acc[4][8];
#pragma unroll
    for (int q = 0; q < 4; q++)
#pragma unroll
        for (int f = 0; f < 8; f++) acc[q][f] = zero4();
    bf16x8 aR[4][2], bR[2][2][2];

    const int NT = K >> 6;

    auto stA = [&](int buf, int kt) {
        long k0 = (long)kt << 6;
#pragma unroll
        for (int i = 0; i < 4; i++)
            gload16(A + (long)rA[i] * K + k0 + scol, &sA[buf][0] + i * 4096 + woff);
    };
    auto stB = [&](int buf, int kt) {
        long k0 = (long)kt << 6;
#pragma unroll
        for (int i = 0; i < 4; i++)
            gload16(Bt + (long)rB[i] * K + k0 + scol, &sB[buf][0] + i * 4096 + woff);
    };

    // prologue: tiles 0,1
    stB(0, 0); stA(0, 0); stB(1, 1); stA(1, 1);
    asm volatile("s_waitcnt vmcnt(8)" ::: "memory");   // tile 0 landed
    bar();

    for (int t = 0; t < NT; t++) {
        const bf16_t* cA = &sA[t & 1][0];
        const bf16_t* cB = &sB[t & 1][0];
        bool st = (t + 2) < NT;

        // ---- p0: read A(mh0) + B(nh0), MFMA q00 ----
#pragma unroll
        for (int mf = 0; mf < 4; mf++)
#pragma unroll
            for (int ks = 0; ks < 2; ks++) {
                int r = wm + mf * 16 + la, gl = ks * 4 + lb;
                aR[mf][ks] = *(const bf16x8*)(cA + r * 64 + ((gl ^ (r & 7)) << 3));
            }
#pragma unroll
        for (int nf = 0; nf < 2; nf++)
#pragma unroll
            for (int ks = 0; ks < 2; ks++) {
                int r = wn + nf * 16 + la, gl = ks * 4 + lb;
                bR[0][nf][ks] = *(const bf16x8*)(cB + r * 64 + ((gl ^ (r & 7)) << 3));
            }
        bar();
        asm volatile("s_waitcnt lgkmcnt(0)" ::: "memory");
        __builtin_amdgcn_sched_barrier(0);
        __builtin_amdgcn_s_setprio(1);
        MFMAQ(0, 0)
        __builtin_amdgcn_s_setprio(0);
        bar();

        // ---- p1: read B(nh1), MFMA q01 ----
#pragma unroll
        for (int nf = 0; nf < 2; nf++)
#pragma unroll
            for (int ks = 0; ks < 2; ks++) {
                int r = wn + 32 + nf * 16 + la, gl = ks * 4 + lb;
                bR[1][nf][ks] = *(const bf16x8*)(cB + r * 64 + ((gl ^ (r & 7)) << 3));
            }
        bar();
        asm volatile("s_waitcnt lgkmcnt(0)" ::: "memory");
        __builtin_amdgcn_sched_barrier(0);
        __builtin_amdgcn_s_setprio(1);
        MFMAQ(0, 1)
        __builtin_amdgcn_s_setprio(0);
        bar();

        // ---- p2: read A(mh1), stage B(t+2), MFMA q11 ----
#pragma unroll
        for (int mf = 0; mf < 4; mf++)
#pragma unroll
            for (int ks = 0; ks < 2; ks++) {
                int r = wm + 64 + mf * 16 + la, gl = ks * 4 + lb;
                aR[mf][ks] = *(const bf16x8*)(cA + r * 64 + ((gl ^ (r & 7)) << 3));
            }
        if (st) stB(t & 1, t + 2);
        bar();
        asm volatile("s_waitcnt lgkmcnt(0)" ::: "memory");
        __builtin_amdgcn_sched_barrier(0);
        __builtin_amdgcn_s_setprio(1);
        MFMAQ(1, 1)
        __builtin_amdgcn_s_setprio(0);
        bar();

        // ---- p3: stage A(t+2), MFMA q10 (register-only), publish tile t+1 ----
        if (st) stA(t & 1, t + 2);
        __builtin_amdgcn_s_setprio(1);
        MFMAQ(1, 0)
        __builtin_amdgcn_s_setprio(0);
        if (t < NT - 1) {
            if (st) asm volatile("s_waitcnt vmcnt(8)" ::: "memory");
            else    asm volatile("s_waitcnt vmcnt(0)" ::: "memory");
            bar();
        }
    }

    // epilogue
#pragma unroll
    for (int mh = 0; mh < 2; mh++)
#pragma unroll
        for (int nh = 0; nh < 2; nh++)
#pragma unroll
            for (int mf = 0; mf < 4; mf++)
#pragma unroll
                for (int nf = 0; nf < 2; nf++) {
                    int ib = bm + wm + mh * 64 + mf * 16 + lb * 4;
                    int jb = bn + wn + nh * 32 + nf * 16 + la;
                    float bv = (MODE == 0) ? 0.f : bias[jb];
                    f32x4 v = acc[mh * 2 + nh][mf * 2 + nf];
#pragma unroll
                    for (int rr = 0; rr < 4; rr++) {
                        int i = ib + rr;
                        if (i >= M) continue;
                        if (MODE == 0) {
                            Cb[(long)i * N + jb] = (bf16_t)v[rr];
                        } else if (MODE == 1) {
                            Cf[(long)i * N + jb] += v[rr] + bv;
                        } else {
                            float u = v[rr] + bv;
                            Cb[(long)i * N + jb] = (bf16_t)(0.5f * u * (1.f + erff(u * 0.70710678118f)));
                        }
                    }
                }
}

// ---------------- head GEMM: 128x128, 2-phase dbuf (tiny, M=32) ----------------
__global__ __launch_bounds__(256) void gemm_h(const bf16_t* __restrict__ A,
                                              const bf16_t* __restrict__ Bt,
                                              const float* __restrict__ bias,
                                              float* __restrict__ Cf,
                                              int M, int N, int K) {
    __shared__ bf16_t sA[2][128][32];
    __shared__ bf16_t sB[2][128][32];
    int tid = threadIdx.x;
    int bm = blockIdx.x * 128, bn = blockIdx.y * 128;
    int wave = tid >> 6, lane = tid & 63;
    int wm = (wave >> 1) * 64, wn = (wave & 1) * 64;
    int la = lane & 15, lb = lane >> 4;
    int rowA[2], rowB[2], colE[2];
#pragma unroll
    for (int q = 0; q < 2; q++) {
        int li = (wave * 2 + q) * 64 + lane;
        int row = li >> 2;
        colE[q] = (li & 3) * 8;
        int ar = bm + row; if (ar > M - 1) ar = M - 1;
        int br = bn + row; if (br > N - 1) br = N - 1;
        rowA[q] = ar; rowB[q] = br;
    }
    f32x4 acc[4][4];
#pragma unroll
    for (int m = 0; m < 4; m++)
#pragma unroll
        for (int n = 0; n < 4; n++) acc[m][n] = zero4();
    int nt = K >> 5;
#pragma unroll
    for (int q = 0; q < 2; q++) {
        gload16(A  + (long)rowA[q] * K + colE[q], &sA[0][0][0] + (wave * 2 + q) * 512);
        gload16(Bt + (long)rowB[q] * K + colE[q], &sB[0][0][0] + (wave * 2 + q) * 512);
    }
    __syncthreads();
    for (int t = 0; t < nt; t++) {
        int cur = t & 1;
        if (t + 1 < nt) {
            int k0 = (t + 1) << 5;
#pragma unroll
            for (int q = 0; q < 2; q++) {
                gload16(A  + (long)rowA[q] * K + k0 + colE[q], &sA[cur ^ 1][0][0] + (wave * 2 + q) * 512);
                gload16(Bt + (long)rowB[q] * K + k0 + colE[q], &sB[cur ^ 1][0][0] + (wave * 2 + q) * 512);
            }
        }
        bf16x8 af[4], bfr[4];
#pragma unroll
        for (int m = 0; m < 4; m++) af[m]  = *(const bf16x8*)&sA[cur][wm + m * 16 + la][lb * 8];
#pragma unroll
        for (int n = 0; n < 4; n++) bfr[n] = *(const bf16x8*)&sB[cur][wn + n * 16 + la][lb * 8];
#pragma unroll
        for (int m = 0; m < 4; m++)
#pragma unroll
            for (int n = 0; n < 4; n++)
                acc[m][n] = mfma16(af[m], bfr[n], acc[m][n]);
        __syncthreads();
    }
#pragma unroll
    for (int m = 0; m < 4; m++) {
#pragma unroll
        for (int n = 0; n < 4; n++) {
            int ib = bm + wm + m * 16 + lb * 4;
            int jb = bn + wn + n * 16 + la;
            if (jb >= N) continue;
            float bv = bias[jb];
#pragma unroll
            for (int r = 0; r < 4; r++) {
                int i = ib + r;
                if (i >= M) continue;
                Cf[(long)i * N + jb] = acc[m][n][r] + bv;
            }
        }
    }
}

// ---------------- QK^T * scale -> dots (fp32, padded NP) ----------------
__global__ __launch_bounds__(256) void qk_k(const bf16_t* __restrict__ qkv,
                                            float* __restrict__ dots) {
    int bh = blockIdx.z;
    int b = bh / HEADS, h = bh % HEADS;
    int i0 = blockIdx.x * 64, j0 = blockIdx.y * 64;
    __shared__ bf16_t sQ[64][32], sK[64][32];
    int tid = threadIdx.x, wave = tid >> 6, lane = tid & 63;
    int wm = (wave >> 1) * 32, wn = (wave & 1) * 32;
    int la = lane & 15, lb = lane >> 4;
    f32x4 acc[2][2];
#pragma unroll
    for (int m = 0; m < 2; m++)
#pragma unroll
        for (int n = 0; n < 2; n++) acc[m][n] = zero4();

    int row = tid >> 2, col = (tid & 3) * 8;
    int qi = i0 + row; if (qi > SEQ - 1) qi = SEQ - 1;
    int kj = j0 + row; if (kj > SEQ - 1) kj = SEQ - 1;
    const bf16_t* qsrc = qkv + (((b * SEQ + qi) * 3 + 0) * HEADS + h) * DH + col;
    const bf16_t* ksrc = qkv + (((b * SEQ + kj) * 3 + 1) * HEADS + h) * DH + col;

#pragma unroll
    for (int d0 = 0; d0 < 64; d0 += 32) {
        *(bf16x8*)&sQ[row][col] = *(const bf16x8*)(qsrc + d0);
        *(bf16x8*)&sK[row][col] = *(const bf16x8*)(ksrc + d0);
        __syncthreads();
        bf16x8 af[2], bfr[2];
#pragma unroll
        for (int m = 0; m < 2; m++) af[m]  = *(const bf16x8*)&sQ[wm + m * 16 + la][lb * 8];
#pragma unroll
        for (int n = 0; n < 2; n++) bfr[n] = *(const bf16x8*)&sK[wn + n * 16 + la][lb * 8];
#pragma unroll
        for (int m = 0; m < 2; m++)
#pragma unroll
            for (int n = 0; n < 2; n++)
                acc[m][n] = mfma16(af[m], bfr[n], acc[m][n]);
        __syncthreads();
    }
#pragma unroll
    for (int m = 0; m < 2; m++)
#pragma unroll
        for (int n = 0; n < 2; n++)
#pragma unroll
            for (int r = 0; r < 4; r++) {
                int i = i0 + wm + m * 16 + lb * 4 + r;
                int j = j0 + wn + n * 16 + la;
                if (i < SEQ && j < SEQ)
                    dots[((long)bh * SEQ + i) * NP + j] = acc[m][n][r] * 0.125f;
            }
}

// ---------------- fused softmax + re-attention (head mix + LN) -> attn2 (bf16) ----------------
__global__ __launch_bounds__(256) void smre_k(const float* __restrict__ dots,
                                              const float* __restrict__ W,
                                              const float* __restrict__ gg,
                                              const float* __restrict__ bb,
                                              bf16_t* __restrict__ attn2) {
    __shared__ float sm[HEADS][NP];
    __shared__ float sW[HEADS * HEADS];
    __shared__ float sg[HEADS], sb[HEADS];
    int tid = threadIdx.x;
    if (tid < HEADS * HEADS) sW[tid] = W[tid];
    if (tid < HEADS) { sg[tid] = gg[tid]; sb[tid] = bb[tid]; }
    int bi = blockIdx.x;             // b*SEQ + i
    int b = bi / SEQ, i = bi % SEQ;
    int wave = tid >> 6, lane = tid & 63;

    for (int h = wave; h < HEADS; h += 4) {
        const float* p = dots + ((long)(b * HEADS + h) * SEQ + i) * NP;
        float v[4], e[4];
#pragma unroll
        for (int q = 0; q < 4; q++) { int j = lane + 64 * q; v[q] = (j < SEQ) ? p[j] : -3.0e38f; }
        float mx = fmaxf(fmaxf(v[0], v[1]), fmaxf(v[2], v[3]));
#pragma unroll
        for (int o = 1; o < 64; o <<= 1) mx = fmaxf(mx, __shfl_xor(mx, o));
        float s = 0.f;
#pragma unroll
        for (int q = 0; q < 4; q++) {
            int j = lane + 64 * q;
            e[q] = (j < SEQ) ? __expf(v[q] - mx) : 0.f;
            s += e[q];
        }
#pragma unroll
        for (int o = 1; o < 64; o <<= 1) s += __shfl_xor(s, o);
        float inv = 1.f / s;
#pragma unroll
        for (int q = 0; q < 4; q++) { int j = lane + 64 * q; if (j < NP) sm[h][j] = e[q] * inv; }
    }
    __syncthreads();

    int j = tid;
    if (j >= NP) return;
    bool valid = j < SEQ;
    float vals[HEADS];
#pragma unroll
    for (int h = 0; h < HEADS; h++) vals[h] = valid ? sm[h][j] : 0.f;
    float mix[HEADS];
    float s = 0.f, sq = 0.f;
#pragma unroll
    for (int g = 0; g < HEADS; g++) {
        float a = 0.f;
#pragma unroll
        for (int h = 0; h < HEADS; h++) a += vals[h] * sW[h * HEADS + g];
        mix[g] = a; s += a; sq += a * a;
    }
    float m  = s * (1.f / 12.f);
    float rs = rsqrtf(sq * (1.f / 12.f) - m * m + 1e-5f);
    long base = ((long)(b * HEADS) * SEQ + i) * NP + j;
    const long hs = (long)SEQ * NP;
#pragma unroll
    for (int g = 0; g < HEADS; g++) {
        float o = valid ? ((mix[g] - m) * rs * sg[g] + sb[g]) : 0.f;
        attn2[base + g * hs] = (bf16_t)o;
    }
}

// ---------------- PV: out[b,h,i,d] = sum_j attn2 * v  -> aout[b,i,h*64+d] (bf16) ----------------
__global__ __launch_bounds__(256) void pv_k(const bf16_t* __restrict__ attn2,
                                            const bf16_t* __restrict__ qkv,
                                            bf16_t* __restrict__ aout) {
    int bh = blockIdx.y;
    int b = bh / HEADS, h = bh % HEADS;
    int i0 = blockIdx.x * 64;
    __shared__ bf16_t sP[64][32];
    __shared__ bf16_t sVt[64][32];   // logical [d][j], XOR-swizzled on j-blocks
    int tid = threadIdx.x, wave = tid >> 6, lane = tid & 63;
    int wm = (wave >> 1) * 32, wn = (wave & 1) * 32;
    int la = lane & 15, lb = lane >> 4;
    f32x4 acc[2][2];
#pragma unroll
    for (int m = 0; m < 2; m++)
#pragma unroll
        for (int n = 0; n < 2; n++) acc[m][n] = zero4();

    int prow = tid >> 2, pcol = (tid & 3) * 8;
    int pi = i0 + prow; if (pi > SEQ - 1) pi = SEQ - 1;
    const bf16_t* psrc = attn2 + ((long)bh * SEQ + pi) * NP + pcol;
    int jl = tid >> 3, dblk = (tid & 7) * 8;
    int jlx = jl ^ ((tid & 3) << 3);

    for (int j0 = 0; j0 < NP; j0 += 32) {
        *(bf16x8*)&sP[prow][pcol] = *(const bf16x8*)(psrc + j0);
        int jg = j0 + jl;
        bf16x8 vv;
#pragma unroll
        for (int e = 0; e < 8; e++) vv[e] = (bf16_t)0.f;
        if (jg < SEQ)
            vv = *(const bf16x8*)(qkv + (((b * SEQ + jg) * 3 + 2) * HEADS + h) * DH + dblk);
#pragma unroll
        for (int e = 0; e < 8; e++) sVt[dblk + e][jlx] = vv[e];
        __syncthreads();
        bf16x8 af[2], bfr[2];
#pragma unroll
        for (int m = 0; m < 2; m++) af[m] = *(const bf16x8*)&sP[wm + m * 16 + la][lb * 8];
#pragma unroll
        for (int n = 0; n < 2; n++) {
            int rowd = wn + n * 16 + la;
            int colj = (lb * 8) ^ (((rowd >> 3) & 3) << 3);
            bfr[n] = *(const bf16x8*)&sVt[rowd][colj];
        }
#pragma unroll
        for (int m = 0; m < 2; m++)
#pragma unroll
            for (int n = 0; n < 2; n++)
                acc[m][n] = mfma16(af[m], bfr[n], acc[m][n]);
        __syncthreads();
    }
#pragma unroll
    for (int m = 0; m < 2; m++)
#pragma unroll
        for (int n = 0; n < 2; n++)
#pragma unroll
            for (int r = 0; r < 4; r++) {
                int i = i0 + wm + m * 16 + lb * 4 + r;
                int d = wn + n * 16 + la;
                if (i < SEQ)
                    aout[((long)b * SEQ + i) * DIM + h * DH + d] = (bf16_t)acc[m][n][r];
            }
}

// ---------------- host orchestration ----------------
extern "C" void kernel_launch(void* const* d_in, const int* in_sizes, int n_in,
                              void* d_out, int out_size, void* d_ws, size_t ws_size,
                              hipStream_t stream) {
    const float* x        = (const float*)d_in[0];
    const float* cls      = (const float*)d_in[1];
    const float* ln1_g    = (const float*)d_in[2];
    const float* ln1_b    = (const float*)d_in[3];
    const float* w_qkv    = (const float*)d_in[4];
    const float* reattn_w = (const float*)d_in[5];
    const float* reattn_g = (const float*)d_in[6];
    const float* reattn_b = (const float*)d_in[7];
    const float* w_out    = (const float*)d_in[8];
    const float* b_out    = (const float*)d_in[9];
    const float* ln2_g    = (const float*)d_in[10];
    const float* ln2_b    = (const float*)d_in[11];
    const float* w1       = (const float*)d_in[12];
    const float* b1       = (const float*)d_in[13];
    const float* w2       = (const float*)d_in[14];
    const float* b2       = (const float*)d_in[15];
    const float* lnf_g    = (const float*)d_in[16];
    const float* lnf_b    = (const float*)d_in[17];
    const float* w_head   = (const float*)d_in[18];
    const float* b_head   = (const float*)d_in[19];
    float* out = (float*)d_out;

    char* p = (char*)d_ws;
    auto alloc = [&](size_t bytes) -> char* {
        char* r = p;
        p += (bytes + 255) & ~(size_t)255;
        return r;
    };
    bf16_t* wt      = (bf16_t*)alloc(2ULL * MLPD * DIM);
    bf16_t* wt_head = (bf16_t*)alloc(2ULL * FEAT * DIM);
    float*  xbuf    = (float*)alloc(4ULL * TOK * DIM);
    bf16_t* h_ln    = (bf16_t*)alloc(2ULL * TOK * DIM);
    bf16_t* qkv     = (bf16_t*)alloc(2ULL * TOK * 3 * DIM);
    float*  dots    = (float*)alloc(4ULL * BATCH * HEADS * SEQ * NP);
    bf16_t* h_mid   = (bf16_t*)dots;                               // lifetime-overlaid with dots
    bf16_t* attn2   = (bf16_t*)alloc(2ULL * BATCH * HEADS * SEQ * NP);
    bf16_t* aout    = (bf16_t*)alloc(2ULL * TOK * DIM);

    dim3 B256(256), B512(512);
    const int GM = (TOK + 255) / 256;   // 25
    concat_k<<<(TOK * DIM) / 256, B256, 0, stream>>>(x, cls, xbuf);
    tcvt_k<<<dim3((FEAT + 31) / 32, DIM / 32), B256, 0, stream>>>(w_head, wt_head, DIM, FEAT);

    for (int l = 0; l < DEPTH; l++) {
        ln_k<<<TOK, B256, 0, stream>>>(xbuf, DIM, ln1_g + l * DIM, ln1_b + l * DIM, h_ln);
        tcvt_k<<<dim3(2304 / 32, DIM / 32), B256, 0, stream>>>(w_qkv + (long)l * DIM * 2304, wt, DIM, 2304);
        gemm8_k<0><<<GM * 9, B512, 0, stream>>>(h_ln, wt, nullptr, nullptr, qkv, TOK, 2304, DIM, 9);
        qk_k<<<dim3(4, 4, BATCH * HEADS), B256, 0, stream>>>(qkv, dots);
        smre_k<<<TOK, B256, 0, stream>>>(
            dots, reattn_w + l * HEADS * HEADS, reattn_g + l * HEADS, reattn_b + l * HEADS, attn2);
        pv_k<<<dim3(4, BATCH * HEADS), B256, 0, stream>>>(attn2, qkv, aout);
        tcvt_k<<<dim3(DIM / 32, DIM / 32), B256, 0, stream>>>(w_out + (long)l * DIM * DIM, wt, DIM, DIM);
        gemm8_k<1><<<GM * 3, B512, 0, stream>>>(aout, wt, b_out + l * DIM, xbuf, nullptr, TOK, DIM, DIM, 3);
        ln_k<<<TOK, B256, 0, stream>>>(xbuf, DIM, ln2_g + l * DIM, ln2_b + l * DIM, h_ln);
        tcvt_k<<<dim3(MLPD / 32, DIM / 32), B256, 0, stream>>>(w1 + (long)l * DIM * MLPD, wt, DIM, MLPD);
        gemm8_k<2><<<GM * 12, B512, 0, stream>>>(h_ln, wt, b1 + l * MLPD, nullptr, h_mid, TOK, MLPD, DIM, 12);
        tcvt_k<<<dim3(DIM / 32, MLPD / 32), B256, 0, stream>>>(w2 + (long)l * MLPD * DIM, wt, MLPD, DIM);
        gemm8_k<1><<<GM * 3, B512, 0, stream>>>(h_mid, wt, b2 + l * DIM, xbuf, nullptr, TOK, DIM, MLPD, 3);
    }

    ln_k<<<BATCH, B256, 0, stream>>>(xbuf, (long)SEQ * DIM, lnf_g, lnf_b, h_ln);
    gemm_h<<<dim3(1, 8), B256, 0, stream>>>(h_ln, wt_head, b_head, out, BATCH, FEAT, DIM);
}

// Round 9
// 2014.526 us; speedup vs baseline: 1.3920x; 1.3920x over previous
//
#include <hip/hip_runtime.h>
#include <cstdint>

typedef __bf16 bf16_t;
typedef __bf16 bf16x8 __attribute__((ext_vector_type(8)));
typedef float  f32x4  __attribute__((ext_vector_type(4)));
typedef unsigned int u32;

#define DEPTH 6
#define HEADS 12
#define DH    64
#define DIM   768
#define MLPD  3072
#define FEAT  1000
#define BATCH 32
#define SEQ   197
#define NP    224          // padded j stride for attention matrices
#define TOK   (BATCH*SEQ)  // 6304

__device__ __forceinline__ f32x4 zero4() {
    f32x4 z; z[0] = 0.f; z[1] = 0.f; z[2] = 0.f; z[3] = 0.f; return z;
}

__device__ __forceinline__ f32x4 mfma16(bf16x8 a, bf16x8 b, f32x4 c) {
    return __builtin_amdgcn_mfma_f32_16x16x32_bf16(a, b, c, 0, 0, 0);
}

// async global->LDS, 16B per lane. lds base must be wave-uniform; HW adds lane*16.
typedef const __attribute__((address_space(1))) u32* gas_ptr;
typedef __attribute__((address_space(3))) u32*       las_ptr;
__device__ __forceinline__ void gload16(const bf16_t* g, bf16_t* l) {
    __builtin_amdgcn_global_load_lds((gas_ptr)g, (las_ptr)l, 16, 0, 0);
}

// bijective inverse-XCD chunking (m204): consecutive logical ids share an XCD L2.
__device__ __forceinline__ int xcd_logical(int L, int nblk) {
    int q = nblk >> 3, r = nblk & 7, xcd = L & 7;
    return (xcd < r ? xcd * (q + 1) : r * (q + 1) + (xcd - r) * q) + (L >> 3);
}

// ---------------- concat cls + x -> xbuf ----------------
__global__ __launch_bounds__(256) void concat_k(const float* __restrict__ x,
                                                const float* __restrict__ cls,
                                                float* __restrict__ xbuf) {
    int idx = blockIdx.x * 256 + threadIdx.x;      // exactly 6304*768 threads
    int col = idx % DIM;
    int row = idx / DIM;
    int b = row / SEQ, p = row % SEQ;
    xbuf[idx] = (p == 0) ? cls[col] : x[(b * 196 + p - 1) * DIM + col];
}

// ---------------- transpose + fp32->bf16:  W[K][N] -> Wt[N][K] ----------------
__global__ __launch_bounds__(256) void tcvt_k(const float* __restrict__ W,
                                              bf16_t* __restrict__ Wt,
                                              int K, int N) {
    __shared__ float t[32][33];
    int n0 = blockIdx.x * 32, k0 = blockIdx.y * 32;
    int c = threadIdx.x & 31, r = threadIdx.x >> 5;
#pragma unroll
    for (int i = 0; i < 4; i++) {
        int k = k0 + r + i * 8, n = n0 + c;        // K is always a multiple of 32
        t[r + i * 8][c] = (n < N) ? W[k * N + n] : 0.f;
    }
    __syncthreads();
#pragma unroll
    for (int i = 0; i < 4; i++) {
        int n = n0 + r + i * 8, k = k0 + c;
        if (n < N) Wt[n * K + k] = (bf16_t)t[c][r + i * 8];
    }
}

// ---------------- row LayerNorm over 768 cols, fp32 in -> bf16 out ----------------
__global__ __launch_bounds__(256) void ln_k(const float* __restrict__ x, long row_stride,
                                            const float* __restrict__ g,
                                            const float* __restrict__ b,
                                            bf16_t* __restrict__ out) {
    int row = blockIdx.x;
    const float* xr = x + (long)row * row_stride;
    int t = threadIdx.x;
    float v0 = xr[t], v1 = xr[t + 256], v2 = xr[t + 512];
    float s  = v0 + v1 + v2;
    float sq = v0 * v0 + v1 * v1 + v2 * v2;
#pragma unroll
    for (int o = 1; o < 64; o <<= 1) { s += __shfl_xor(s, o); sq += __shfl_xor(sq, o); }
    __shared__ float ss[4], sqs[4];
    int w = t >> 6;
    if ((t & 63) == 0) { ss[w] = s; sqs[w] = sq; }
    __syncthreads();
    s  = ss[0] + ss[1] + ss[2] + ss[3];
    sq = sqs[0] + sqs[1] + sqs[2] + sqs[3];
    float m  = s * (1.f / 768.f);
    float rs = rsqrtf(sq * (1.f / 768.f) - m * m + 1e-5f);
    bf16_t* orow = out + (long)row * DIM;
    orow[t]       = (bf16_t)((v0 - m) * rs * g[t]       + b[t]);
    orow[t + 256] = (bf16_t)((v1 - m) * rs * g[t + 256] + b[t + 256]);
    orow[t + 512] = (bf16_t)((v2 - m) * rs * g[t + 512] + b[t + 512]);
}

// ============ big GEMM: 128x128 tile, BK=64, 4 waves, ring-2, depth-1 ============
// Interval model: time ~ intervals x fixed-cost; BK=64 halves intervals vs BK=32.
// Ledger: prologue stages tile 0 (8 loads). Iter t: vmcnt(0) retires tile t's loads
// (issued iter t-1 post-barrier); barrier publishes; stage(t+1) overwrites the buffer
// read at iter t-1 (its ds_reads completed before their MFMAs, which precede this
// barrier -> safe); compute t.
// Swizzle (both-sides, r6-verified invariant): 16B granule s at row r holds logical
// granule s^(r&7); staged via pre-swizzled global col, read via granule^(la&7).
// MODE 0: Cb=acc; 1: Cf+=acc+bias; 2: Cb=gelu(acc+bias); 3: Cf[kc*M*N+..]=acc (split-K)
template <int MODE>
__global__ __launch_bounds__(256, 2) void gemm_k(const bf16_t* __restrict__ A,
                                                 const bf16_t* __restrict__ Bt,
                                                 const float* __restrict__ bias,
                                                 float* __restrict__ Cf,
                                                 bf16_t* __restrict__ Cb,
                                                 int M, int N, int Kstride, int Klen,
                                                 int nN, int nblk) {
    __shared__ bf16_t sA[2][128 * 64];   // 32 KB
    __shared__ bf16_t sB[2][128 * 64];   // 32 KB
    int tid = threadIdx.x;
    int kc = blockIdx.x / nblk;                       // split-K chunk
    int g  = xcd_logical(blockIdx.x % nblk, nblk);
    int bm = (g / nN) * 128, bn = (g % nN) * 128;
    long koff = (long)kc * Klen;
    int wave = tid >> 6, lane = tid & 63;
    int wm = (wave >> 1) * 64, wn = (wave & 1) * 64;
    int la = lane & 15, lb = lane >> 4;

    // staging geometry: per operand tile 16KB = 4 issues of 4KB. issue i covers rows
    // i*32..i*32+31 (row = i*32 + (tid>>3), slot tid&7). LDS layout: row*64 + slot*8
    // (linear; per-wave dest base = i*2048 + wave*512, HW adds lane*16B).
    int srow = tid >> 3;                              // 0..31
    int scol = ((tid & 7) ^ (srow & 7)) * 8;          // pre-swizzled source col (elems)
    int rA[4], rB[4];
#pragma unroll
    for (int i = 0; i < 4; i++) {
        int r = bm + i * 32 + srow; rA[i] = (r < M) ? r : M - 1;
        rB[i] = bn + i * 32 + srow;                   // N multiple of 128
    }
    int wbase = wave * 512;                           // wave-uniform LDS elem base

    f32x4 acc[4][4];
#pragma unroll
    for (int m = 0; m < 4; m++)
#pragma unroll
        for (int n = 0; n < 4; n++) acc[m][n] = zero4();

    const int NT = Klen >> 6;
    int swz = la & 7;                                 // read-side granule XOR

    auto stage = [&](int buf, int kt) {
        long k0 = koff + ((long)kt << 6);
#pragma unroll
        for (int i = 0; i < 4; i++)
            gload16(A + (long)rA[i] * Kstride + k0 + scol, &sA[buf][i * 2048 + wbase]);
#pragma unroll
        for (int i = 0; i < 4; i++)
            gload16(Bt + (long)rB[i] * Kstride + k0 + scol, &sB[buf][i * 2048 + wbase]);
    };

    stage(0, 0);

    for (int t = 0; t < NT; t++) {
        int cur = t & 1;
        asm volatile("s_waitcnt vmcnt(0)" ::: "memory");
        __builtin_amdgcn_s_barrier();
        asm volatile("" ::: "memory");
        if (t + 1 < NT) stage(cur ^ 1, t + 1);

        const bf16_t* cA = &sA[cur][0];
        const bf16_t* cB = &sB[cur][0];
#pragma unroll
        for (int ks = 0; ks < 2; ks++) {
            bf16x8 aR[4], bR[4];
            int gr = ((ks * 4 + lb) ^ swz) << 3;      // swizzled granule elem offset
#pragma unroll
            for (int mf = 0; mf < 4; mf++)
                aR[mf] = *(const bf16x8*)(cA + (wm + mf * 16 + la) * 64 + gr);
#pragma unroll
            for (int nf = 0; nf < 4; nf++)
                bR[nf] = *(const bf16x8*)(cB + (wn + nf * 16 + la) * 64 + gr);
            __builtin_amdgcn_s_setprio(1);
#pragma unroll
            for (int mf = 0; mf < 4; mf++)
#pragma unroll
                for (int nf = 0; nf < 4; nf++)
                    acc[mf][nf] = mfma16(aR[mf], bR[nf], acc[mf][nf]);
            __builtin_amdgcn_s_setprio(0);
        }
    }

    long kout = (long)kc * M * (long)N;               // split-K output chunk offset
#pragma unroll
    for (int mf = 0; mf < 4; mf++) {
#pragma unroll
        for (int nf = 0; nf < 4; nf++) {
            int ib = bm + wm + mf * 16 + lb * 4;
            int jb = bn + wn + nf * 16 + la;
            float bvv = (MODE == 1 || MODE == 2) ? bias[jb] : 0.f;
#pragma unroll
            for (int rr = 0; rr < 4; rr++) {
                int i = ib + rr;
                if (i >= M) continue;
                float v = acc[mf][nf][rr];
                if (MODE == 0) {
                    Cb[(long)i * N + jb] = (bf16_t)v;
                } else if (MODE == 1) {
                    Cf[(long)i * N + jb] += v + bvv;
                } else if (MODE == 2) {
                    float u = v + bvv;
                    Cb[(long)i * N + jb] = (bf16_t)(0.5f * u * (1.f + erff(u * 0.70710678118f)));
                } else {
                    Cf[kout + (long)i * N + jb] = v;
                }
            }
        }
    }
}

// ---------------- split-K reduce: xbuf += p0 + p1 + bias ----------------
__global__ __launch_bounds__(256) void redk_k(float* __restrict__ xbuf,
                                              const float* __restrict__ part,
                                              const float* __restrict__ bias) {
    const long total = (long)TOK * DIM;
    for (long idx = blockIdx.x * 256 + threadIdx.x; idx < total; idx += (long)gridDim.x * 256) {
        int col = (int)(idx % DIM);
        xbuf[idx] += part[idx] + part[idx + total] + bias[col];
    }
}

// ---------------- head GEMM: 128x128, 2-phase dbuf (tiny, M=32) ----------------
__global__ __launch_bounds__(256) void gemm_h(const bf16_t* __restrict__ A,
                                              const bf16_t* __restrict__ Bt,
                                              const float* __restrict__ bias,
                                              float* __restrict__ Cf,
                                              int M, int N, int K) {
    __shared__ bf16_t sA[2][128][32];
    __shared__ bf16_t sB[2][128][32];
    int tid = threadIdx.x;
    int bm = blockIdx.x * 128, bn = blockIdx.y * 128;
    int wave = tid >> 6, lane = tid & 63;
    int wm = (wave >> 1) * 64, wn = (wave & 1) * 64;
    int la = lane & 15, lb = lane >> 4;
    int rowA[2], rowB[2], colE[2];
#pragma unroll
    for (int q = 0; q < 2; q++) {
        int li = (wave * 2 + q) * 64 + lane;
        int row = li >> 2;
        colE[q] = (li & 3) * 8;
        int ar = bm + row; if (ar > M - 1) ar = M - 1;
        int br = bn + row; if (br > N - 1) br = N - 1;
        rowA[q] = ar; rowB[q] = br;
    }
    f32x4 acc[4][4];
#pragma unroll
    for (int m = 0; m < 4; m++)
#pragma unroll
        for (int n = 0; n < 4; n++) acc[m][n] = zero4();
    int nt = K >> 5;
#pragma unroll
    for (int q = 0; q < 2; q++) {
        gload16(A  + (long)rowA[q] * K + colE[q], &sA[0][0][0] + (wave * 2 + q) * 512);
        gload16(Bt + (long)rowB[q] * K + colE[q], &sB[0][0][0] + (wave * 2 + q) * 512);
    }
    __syncthreads();
    for (int t = 0; t < nt; t++) {
        int cur = t & 1;
        if (t + 1 < nt) {
            int k0 = (t + 1) << 5;
#pragma unroll
            for (int q = 0; q < 2; q++) {
                gload16(A  + (long)rowA[q] * K + k0 + colE[q], &sA[cur ^ 1][0][0] + (wave * 2 + q) * 512);
                gload16(Bt + (long)rowB[q] * K + k0 + colE[q], &sB[cur ^ 1][0][0] + (wave * 2 + q) * 512);
            }
        }
        bf16x8 af[4], bfr[4];
#pragma unroll
        for (int m = 0; m < 4; m++) af[m]  = *(const bf16x8*)&sA[cur][wm + m * 16 + la][lb * 8];
#pragma unroll
        for (int n = 0; n < 4; n++) bfr[n] = *(const bf16x8*)&sB[cur][wn + n * 16 + la][lb * 8];
#pragma unroll
        for (int m = 0; m < 4; m++)
#pragma unroll
            for (int n = 0; n < 4; n++)
                acc[m][n] = mfma16(af[m], bfr[n], acc[m][n]);
        __syncthreads();
    }
#pragma unroll
    for (int m = 0; m < 4; m++) {
#pragma unroll
        for (int n = 0; n < 4; n++) {
            int ib = bm + wm + m * 16 + lb * 4;
            int jb = bn + wn + n * 16 + la;
            if (jb >= N) continue;
            float bv = bias[jb];
#pragma unroll
            for (int r = 0; r < 4; r++) {
                int i = ib + r;
                if (i >= M) continue;
                Cf[(long)i * N + jb] = acc[m][n][r] + bv;
            }
        }
    }
}

// ---------------- QK^T * scale -> dots (fp32, padded NP) ----------------
__global__ __launch_bounds__(256) void qk_k(const bf16_t* __restrict__ qkv,
                                            float* __restrict__ dots) {
    int bh = blockIdx.z;
    int b = bh / HEADS, h = bh % HEADS;
    int i0 = blockIdx.x * 64, j0 = blockIdx.y * 64;
    __shared__ bf16_t sQ[64][32], sK[64][32];
    int tid = threadIdx.x, wave = tid >> 6, lane = tid & 63;
    int wm = (wave >> 1) * 32, wn = (wave & 1) * 32;
    int la = lane & 15, lb = lane >> 4;
    f32x4 acc[2][2];
#pragma unroll
    for (int m = 0; m < 2; m++)
#pragma unroll
        for (int n = 0; n < 2; n++) acc[m][n] = zero4();

    int row = tid >> 2, col = (tid & 3) * 8;
    int qi = i0 + row; if (qi > SEQ - 1) qi = SEQ - 1;
    int kj = j0 + row; if (kj > SEQ - 1) kj = SEQ - 1;
    const bf16_t* qsrc = qkv + (((b * SEQ + qi) * 3 + 0) * HEADS + h) * DH + col;
    const bf16_t* ksrc = qkv + (((b * SEQ + kj) * 3 + 1) * HEADS + h) * DH + col;

#pragma unroll
    for (int d0 = 0; d0 < 64; d0 += 32) {
        *(bf16x8*)&sQ[row][col] = *(const bf16x8*)(qsrc + d0);
        *(bf16x8*)&sK[row][col] = *(const bf16x8*)(ksrc + d0);
        __syncthreads();
        bf16x8 af[2], bfr[2];
#pragma unroll
        for (int m = 0; m < 2; m++) af[m]  = *(const bf16x8*)&sQ[wm + m * 16 + la][lb * 8];
#pragma unroll
        for (int n = 0; n < 2; n++) bfr[n] = *(const bf16x8*)&sK[wn + n * 16 + la][lb * 8];
#pragma unroll
        for (int m = 0; m < 2; m++)
#pragma unroll
            for (int n = 0; n < 2; n++)
                acc[m][n] = mfma16(af[m], bfr[n], acc[m][n]);
        __syncthreads();
    }
#pragma unroll
    for (int m = 0; m < 2; m++)
#pragma unroll
        for (int n = 0; n < 2; n++)
#pragma unroll
            for (int r = 0; r < 4; r++) {
                int i = i0 + wm + m * 16 + lb * 4 + r;
                int j = j0 + wn + n * 16 + la;
                if (i < SEQ && j < SEQ)
                    dots[((long)bh * SEQ + i) * NP + j] = acc[m][n][r] * 0.125f;
            }
}

// ---------------- fused softmax + re-attention (head mix + LN) -> attn2 (bf16) ----------------
__global__ __launch_bounds__(256) void smre_k(const float* __restrict__ dots,
                                              const float* __restrict__ W,
                                              const float* __restrict__ gg,
                                              const float* __restrict__ bb,
                                              bf16_t* __restrict__ attn2) {
    __shared__ float sm[HEADS][NP];
    __shared__ float sW[HEADS * HEADS];
    __shared__ float sg[HEADS], sb[HEADS];
    int tid = threadIdx.x;
    if (tid < HEADS * HEADS) sW[tid] = W[tid];
    if (tid < HEADS) { sg[tid] = gg[tid]; sb[tid] = bb[tid]; }
    int bi = blockIdx.x;             // b*SEQ + i
    int b = bi / SEQ, i = bi % SEQ;
    int wave = tid >> 6, lane = tid & 63;

    for (int h = wave; h < HEADS; h += 4) {
        const float* p = dots + ((long)(b * HEADS + h) * SEQ + i) * NP;
        float v[4], e[4];
#pragma unroll
        for (int q = 0; q < 4; q++) { int j = lane + 64 * q; v[q] = (j < SEQ) ? p[j] : -3.0e38f; }
        float mx = fmaxf(fmaxf(v[0], v[1]), fmaxf(v[2], v[3]));
#pragma unroll
        for (int o = 1; o < 64; o <<= 1) mx = fmaxf(mx, __shfl_xor(mx, o));
        float s = 0.f;
#pragma unroll
        for (int q = 0; q < 4; q++) {
            int j = lane + 64 * q;
            e[q] = (j < SEQ) ? __expf(v[q] - mx) : 0.f;
            s += e[q];
        }
#pragma unroll
        for (int o = 1; o < 64; o <<= 1) s += __shfl_xor(s, o);
        float inv = 1.f / s;
#pragma unroll
        for (int q = 0; q < 4; q++) { int j = lane + 64 * q; if (j < NP) sm[h][j] = e[q] * inv; }
    }
    __syncthreads();

    int j = tid;
    if (j >= NP) return;
    bool valid = j < SEQ;
    float vals[HEADS];
#pragma unroll
    for (int h = 0; h < HEADS; h++) vals[h] = valid ? sm[h][j] : 0.f;
    float mix[HEADS];
    float s = 0.f, sq = 0.f;
#pragma unroll
    for (int g = 0; g < HEADS; g++) {
        float a = 0.f;
#pragma unroll
        for (int h = 0; h < HEADS; h++) a += vals[h] * sW[h * HEADS + g];
        mix[g] = a; s += a; sq += a * a;
    }
    float m  = s * (1.f / 12.f);
    float rs = rsqrtf(sq * (1.f / 12.f) - m * m + 1e-5f);
    long base = ((long)(b * HEADS) * SEQ + i) * NP + j;
    const long hs = (long)SEQ * NP;
#pragma unroll
    for (int g = 0; g < HEADS; g++) {
        float o = valid ? ((mix[g] - m) * rs * sg[g] + sb[g]) : 0.f;
        attn2[base + g * hs] = (bf16_t)o;
    }
}

// ---------------- PV: out[b,h,i,d] = sum_j attn2 * v  -> aout[b,i,h*64+d] (bf16) ----------------
__global__ __launch_bounds__(256) void pv_k(const bf16_t* __restrict__ attn2,
                                            const bf16_t* __restrict__ qkv,
                                            bf16_t* __restrict__ aout) {
    int bh = blockIdx.y;
    int b = bh / HEADS, h = bh % HEADS;
    int i0 = blockIdx.x * 64;
    __shared__ bf16_t sP[64][32];
    __shared__ bf16_t sVt[64][32];   // logical [d][j], XOR-swizzled on j-blocks
    int tid = threadIdx.x, wave = tid >> 6, lane = tid & 63;
    int wm = (wave >> 1) * 32, wn = (wave & 1) * 32;
    int la = lane & 15, lb = lane >> 4;
    f32x4 acc[2][2];
#pragma unroll
    for (int m = 0; m < 2; m++)
#pragma unroll
        for (int n = 0; n < 2; n++) acc[m][n] = zero4();

    int prow = tid >> 2, pcol = (tid & 3) * 8;
    int pi = i0 + prow; if (pi > SEQ - 1) pi = SEQ - 1;
    const bf16_t* psrc = attn2 + ((long)bh * SEQ + pi) * NP + pcol;
    int jl = tid >> 3, dblk = (tid & 7) * 8;
    int jlx = jl ^ ((tid & 3) << 3);

    for (int j0 = 0; j0 < NP; j0 += 32) {
        *(bf16x8*)&sP[prow][pcol] = *(const bf16x8*)(psrc + j0);
        int jg = j0 + jl;
        bf16x8 vv;
#pragma unroll
        for (int e = 0; e < 8; e++) vv[e] = (bf16_t)0.f;
        if (jg < SEQ)
            vv = *(const bf16x8*)(qkv + (((b * SEQ + jg) * 3 + 2) * HEADS + h) * DH + dblk);
#pragma unroll
        for (int e = 0; e < 8; e++) sVt[dblk + e][jlx] = vv[e];
        __syncthreads();
        bf16x8 af[2], bfr[2];
#pragma unroll
        for (int m = 0; m < 2; m++) af[m] = *(const bf16x8*)&sP[wm + m * 16 + la][lb * 8];
#pragma unroll
        for (int n = 0; n < 2; n++) {
            int rowd = wn + n * 16 + la;
            int colj = (lb * 8) ^ (((rowd >> 3) & 3) << 3);
            bfr[n] = *(const bf16x8*)&sVt[rowd][colj];
        }
#pragma unroll
        for (int m = 0; m < 2; m++)
#pragma unroll
            for (int n = 0; n < 2; n++)
                acc[m][n] = mfma16(af[m], bfr[n], acc[m][n]);
        __syncthreads();
    }
#pragma unroll
    for (int m = 0; m < 2; m++)
#pragma unroll
        for (int n = 0; n < 2; n++)
#pragma unroll
            for (int r = 0; r < 4; r++) {
                int i = i0 + wm + m * 16 + lb * 4 + r;
                int d = wn + n * 16 + la;
                if (i < SEQ)
                    aout[((long)b * SEQ + i) * DIM + h * DH + d] = (bf16_t)acc[m][n][r];
            }
}

// ---------------- host orchestration ----------------
extern "C" void kernel_launch(void* const* d_in, const int* in_sizes, int n_in,
                              void* d_out, int out_size, void* d_ws, size_t ws_size,
                              hipStream_t stream) {
    const float* x        = (const float*)d_in[0];
    const float* cls      = (const float*)d_in[1];
    const float* ln1_g    = (const float*)d_in[2];
    const float* ln1_b    = (const float*)d_in[3];
    const float* w_qkv    = (const float*)d_in[4];
    const float* reattn_w = (const float*)d_in[5];
    const float* reattn_g = (const float*)d_in[6];
    const float* reattn_b = (const float*)d_in[7];
    const float* w_out    = (const float*)d_in[8];
    const float* b_out    = (const float*)d_in[9];
    const float* ln2_g    = (const float*)d_in[10];
    const float* ln2_b    = (const float*)d_in[11];
    const float* w1       = (const float*)d_in[12];
    const float* b1       = (const float*)d_in[13];
    const float* w2       = (const float*)d_in[14];
    const float* b2       = (const float*)d_in[15];
    const float* lnf_g    = (const float*)d_in[16];
    const float* lnf_b    = (const float*)d_in[17];
    const float* w_head   = (const float*)d_in[18];
    const float* b_head   = (const float*)d_in[19];
    float* out = (float*)d_out;

    char* p = (char*)d_ws;
    auto alloc = [&](size_t bytes) -> char* {
        char* r = p;
        p += (bytes + 255) & ~(size_t)255;
        return r;
    };
    bf16_t* wt      = (bf16_t*)alloc(2ULL * MLPD * DIM);
    bf16_t* wt_head = (bf16_t*)alloc(2ULL * FEAT * DIM);
    float*  xbuf    = (float*)alloc(4ULL * TOK * DIM);
    bf16_t* h_ln    = (bf16_t*)alloc(2ULL * TOK * DIM);
    bf16_t* qkv     = (bf16_t*)alloc(2ULL * TOK * 3 * DIM);
    float*  dots    = (float*)alloc(4ULL * BATCH * HEADS * SEQ * NP);
    bf16_t* h_mid   = (bf16_t*)dots;                               // lifetime-overlaid with dots
    bf16_t* attn2   = (bf16_t*)alloc(2ULL * BATCH * HEADS * SEQ * NP);
    bf16_t* aout    = (bf16_t*)alloc(2ULL * TOK * DIM);
    // split-K partials (2 x TOK x DIM fp32 = 38.7MB) overlay attn2+aout (43.6MB),
    // both dead during MLP2 and fully rewritten next layer.
    float*  part    = (float*)attn2;

    dim3 B256(256);
    const int NM = (TOK + 127) / 128;   // 50
    concat_k<<<(TOK * DIM) / 256, B256, 0, stream>>>(x, cls, xbuf);
    tcvt_k<<<dim3((FEAT + 31) / 32, DIM / 32), B256, 0, stream>>>(w_head, wt_head, DIM, FEAT);

    for (int l = 0; l < DEPTH; l++) {
        ln_k<<<TOK, B256, 0, stream>>>(xbuf, DIM, ln1_g + l * DIM, ln1_b + l * DIM, h_ln);
        tcvt_k<<<dim3(2304 / 32, DIM / 32), B256, 0, stream>>>(w_qkv + (long)l * DIM * 2304, wt, DIM, 2304);
        gemm_k<0><<<NM * 18, B256, 0, stream>>>(h_ln, wt, nullptr, nullptr, qkv,
                                                TOK, 2304, DIM, DIM, 18, NM * 18);
        qk_k<<<dim3(4, 4, BATCH * HEADS), B256, 0, stream>>>(qkv, dots);
        smre_k<<<TOK, B256, 0, stream>>>(
            dots, reattn_w + l * HEADS * HEADS, reattn_g + l * HEADS, reattn_b + l * HEADS, attn2);
        pv_k<<<dim3(4, BATCH * HEADS), B256, 0, stream>>>(attn2, qkv, aout);
        tcvt_k<<<dim3(DIM / 32, DIM / 32), B256, 0, stream>>>(w_out + (long)l * DIM * DIM, wt, DIM, DIM);
        gemm_k<1><<<NM * 6, B256, 0, stream>>>(aout, wt, b_out + l * DIM, xbuf, nullptr,
                                               TOK, DIM, DIM, DIM, 6, NM * 6);
        ln_k<<<TOK, B256, 0, stream>>>(xbuf, DIM, ln2_g + l * DIM, ln2_b + l * DIM, h_ln);
        tcvt_k<<<dim3(MLPD / 32, DIM / 32), B256, 0, stream>>>(w1 + (long)l * DIM * MLPD, wt, DIM, MLPD);
        gemm_k<2><<<NM * 24, B256, 0, stream>>>(h_ln, wt, b1 + l * MLPD, nullptr, h_mid,
                                                TOK, MLPD, DIM, DIM, 24, NM * 24);
        tcvt_k<<<dim3(DIM / 32, MLPD / 32), B256, 0, stream>>>(w2 + (long)l * MLPD * DIM, wt, MLPD, DIM);
        // MLP2: split-K x2 (grid 2x300), partials then fused reduce (+bias, += residual)
        gemm_k<3><<<NM * 6 * 2, B256, 0, stream>>>(h_mid, wt, nullptr, part, nullptr,
                                                   TOK, DIM, MLPD, MLPD / 2, 6, NM * 6);
        redk_k<<<2048, B256, 0, stream>>>(xbuf, part, b2 + l * DIM);
    }

    ln_k<<<BATCH, B256, 0, stream>>>(xbuf, (long)SEQ * DIM, lnf_g, lnf_b, h_ln);
    gemm_h<<<dim3(1, 8), B256, 0, stream>>>(h_ln, wt_head, b_head, out, BATCH, FEAT, DIM);
}